// Round 1
// baseline (453.448 us; speedup 1.0000x reference)
//
#include <hip/hip_runtime.h>

// adder2d: out[b,f,l] = -sum_k |W[f,k] - P[b,k,l]|, P = 3x3/s1/p1 im2col of x.
// Redesign: lane = one m (wave = 64 m), acc[16] filters per lane, P chunk
// (4 ch x 9 taps = 36 f32) in VGPRs reused across 16 filters, W broadcast via
// uniform-address ds_read_b128 from a wave-private 2.3KB LDS panel.
// K split across the 4 waves of the block (32 ch each) -> barrier-free main
// loop, single end-of-kernel LDS tree reduction. No workspace, no combine.

#define B_    16
#define C_    128
#define HH    28
#define WW    28
#define F_    128
#define L_    (HH * WW)            // 784
#define K_    (C_ * 9)             // 1152
#define M_    (B_ * L_)            // 12544 = 196 * 64 exactly
#define NF    16                   // filters per block
#define BCH   4                    // channels per chunk (per wave)
#define KC    (BCH * 9)            // 36 k per chunk
#define NCH   8                    // chunks per wave: 32 ch / BCH
#define RPAD  20                   // reduce-row pad (dwords): conflict-free

__global__ __launch_bounds__(256, 4)
void adder2d_k(const float* __restrict__ x, const float* __restrict__ Wg,
               float* __restrict__ out) {
    __shared__ __align__(16) float s_w[4 * NF * KC];      //  9216 B, W panels
    __shared__ __align__(16) float s_red[4 * 64 * RPAD];  // 20480 B, reduce

    const int t    = threadIdx.x;
    const int lane = t & 63;
    const int wv   = __builtin_amdgcn_readfirstlane(t >> 6);  // scalar wave id
    const int m0   = blockIdx.y * 64;
    const int f0   = blockIdx.x * NF;
    const int m    = m0 + lane;
    const int b    = m / L_;
    const int l    = m - b * L_;
    const int ho   = l / WW;
    const int wo   = l - ho * WW;

    // Per-lane tap byte offsets (incl. batch) + validity as 0/1 float.
    // Invalid taps read a safe in-image address and are multiplied by 0.
    int   voff[9];
    float fm[9];
    #pragma unroll
    for (int r = 0; r < 9; ++r) {
        const int dy = r / 3 - 1;
        const int dx = r - (r / 3) * 3 - 1;
        const bool ok = ((unsigned)(ho + dy) < (unsigned)HH) &&
                        ((unsigned)(wo + dx) < (unsigned)WW);
        const int sp = ok ? (l + dy * WW + dx) : l;
        voff[r] = (b * (C_ * L_) + sp) * 4;
        fm[r]   = ok ? 1.0f : 0.0f;
    }
    // Per-lane W gather byte offsets: lane q=lane+64i -> (fi = q/36, j = q%36)
    int wgoff[9];
    #pragma unroll
    for (int i = 0; i < 9; ++i) {
        const int q  = lane + 64 * i;
        const int fi = q / KC;
        const int j  = q - fi * KC;
        wgoff[i] = ((f0 + fi) * K_ + j) * 4;
    }

    float acc[NF];
    #pragma unroll
    for (int i = 0; i < NF; ++i) acc[i] = 0.0f;

    for (int ch = 0; ch < NCH; ++ch) {
        const int kb = wv * (32 * 9) + ch * KC;          // scalar k base
        // ---- stage W[16][36] for this wave (wave-private, no barrier)
        const char* wsrc = (const char*)(Wg + kb);
        #pragma unroll
        for (int i = 0; i < 9; ++i) {
            s_w[wv * (NF * KC) + lane + 64 * i] = *(const float*)(wsrc + wgoff[i]);
        }
        // ---- load P chunk into registers (masked taps -> 0)
        float p[KC];
        #pragma unroll
        for (int c = 0; c < BCH; ++c) {
            const char* xc = (const char*)(x + (wv * 32 + ch * BCH + c) * L_);
            #pragma unroll
            for (int r = 0; r < 9; ++r) {
                p[c * 9 + r] = *(const float*)(xc + voff[r]) * fm[r];
            }
        }
        // ---- compute: 16 filters x 36 k, W via uniform ds_read broadcast
        #pragma unroll
        for (int fi = 0; fi < NF; ++fi) {
            const float4* wr = (const float4*)&s_w[wv * (NF * KC) + fi * KC];
            float s0 = 0.0f, s1 = 0.0f, s2 = 0.0f, s3 = 0.0f;
            #pragma unroll
            for (int k4 = 0; k4 < KC / 4; ++k4) {
                const float4 w = wr[k4];
                s0 += __builtin_fabsf(p[4 * k4 + 0] - w.x);
                s1 += __builtin_fabsf(p[4 * k4 + 1] - w.y);
                s2 += __builtin_fabsf(p[4 * k4 + 2] - w.z);
                s3 += __builtin_fabsf(p[4 * k4 + 3] - w.w);
            }
            acc[fi] += (s0 + s1) + (s2 + s3);
        }
    }

    // ---- cross-wave tree reduction (single barrier), then store
    #pragma unroll
    for (int g = 0; g < 4; ++g) {
        *(float4*)&s_red[(wv * 64 + lane) * RPAD + g * 4] =
            make_float4(acc[4 * g + 0], acc[4 * g + 1],
                        acc[4 * g + 2], acc[4 * g + 3]);
    }
    __syncthreads();
    // wave wv finalizes filter quad fq = wv for all 64 m of the tile
    const float4 v0 = *(const float4*)&s_red[(0 * 64 + lane) * RPAD + wv * 4];
    const float4 v1 = *(const float4*)&s_red[(1 * 64 + lane) * RPAD + wv * 4];
    const float4 v2 = *(const float4*)&s_red[(2 * 64 + lane) * RPAD + wv * 4];
    const float4 v3 = *(const float4*)&s_red[(3 * 64 + lane) * RPAD + wv * 4];
    const float r0 = -((v0.x + v1.x) + (v2.x + v3.x));
    const float r1 = -((v0.y + v1.y) + (v2.y + v3.y));
    const float r2 = -((v0.z + v1.z) + (v2.z + v3.z));
    const float r3 = -((v0.w + v1.w) + (v2.w + v3.w));
    float* o = out + ((size_t)b * F_ + f0 + wv * 4) * L_ + l;
    o[0 * L_] = r0;
    o[1 * L_] = r1;
    o[2 * L_] = r2;
    o[3 * L_] = r3;
}

extern "C" void kernel_launch(void* const* d_in, const int* in_sizes, int n_in,
                              void* d_out, int out_size, void* d_ws, size_t ws_size,
                              hipStream_t stream) {
    const float* x = (const float*)d_in[0];   // [16,128,28,28]
    const float* W = (const float*)d_in[1];   // [128,128,3,3]
    float* out = (float*)d_out;               // [16,128,28,28]
    (void)d_ws; (void)ws_size;

    dim3 grid(F_ / NF, M_ / 64, 1);           // (8, 196) = 1568 blocks
    adder2d_k<<<grid, 256, 0, stream>>>(x, W, out);
}

// Round 2
// 214.451 us; speedup vs baseline: 2.1145x; 2.1145x over previous
//
#include <hip/hip_runtime.h>

// adder2d: out[b,f,l] = -sum_k |W[f,k] - P[b,k,l]|, P = 3x3/s1/p1 im2col of x.
// Round-0 structure (LDS-tiled, K-split x4 + combine) with register blocking
// widened 4m x 4f -> 4m x 8f (TM=64, TF=128): 3 ds_read_b128 per 64 VALU inst
// (ratio 1.125 vs round-0's 1.5), all-f tile kills x re-fetch redundancy,
// W reads are 16-lane broadcasts (4 distinct addrs/wave) -> ~0 bank conflicts.

#define B_   16
#define C_   128
#define HH   28
#define WW   28
#define F_   128
#define L_   (HH * WW)          // 784
#define K_   (C_ * 9)           // 1152
#define M_   (B_ * L_)          // 12544 = 196 * 64 exactly
#define BC   4                  // channels per LDS chunk
#define KC   (BC * 9)           // 36 k-steps per chunk
#define TM   64                 // m-tile
#define TF   128                // f-tile (all filters)
#define LDP  (TM + 4)           // 68 words
#define LDWR (TF + 4)           // 132 words
#define SPLIT 4                 // K-split factor
#define SLAB  (B_ * F_ * L_)    // 1,605,632 floats per partial slab
#define NMT  (M_ / TM)          // 196 m-tiles, exact

__global__ __launch_bounds__(256, 2)
void adder2d_main(const float* __restrict__ x, const float* __restrict__ Wg,
                  float* __restrict__ dst, int nch, int direct) {
    __shared__ __align__(16) float Pl[KC][LDP];    //  9,792 B
    __shared__ __align__(16) float Wl[KC][LDWR];   // 19,008 B

    const int t  = threadIdx.x;
    const int tx = t & 15;             // m-thread: 4 m each
    const int ty = t >> 4;             // f-thread: 8 f each (16 x 8 = 128)
    const int m0 = blockIdx.x * TM;
    const int c0 = blockIdx.z * nch * BC;   // first channel of this split

    // ---- P staging geometry: thread t stages (k = (t>>6) + 4i, m = t&63), i<9.
    const int mP  = t & 63;
    const int kP0 = t >> 6;
    const int mG  = m0 + mP;           // global m, always < M_ (exact tiling)
    int poff[9];                       // b*C*L + c_local*L + y*28 + xw, or -1
    {
        const int bI = mG / L_;
        const int lP = mG - bI * L_;
        const int ho = lP / WW, wo = lP - (lP / WW) * WW;
        const int bbase = bI * (C_ * L_);
        #pragma unroll
        for (int i = 0; i < 9; ++i) {
            const int kl = kP0 + 4 * i;
            const int cl = kl / 9, r = kl - cl * 9;
            const int kh = r / 3,  kw = r - (r / 3) * 3;
            const int y  = ho + kh - 1, xw = wo + kw - 1;
            const bool v = (y >= 0) && (y < HH) && (xw >= 0) && (xw < WW);
            poff[i] = v ? (bbase + cl * L_ + y * WW + xw) : -1;
        }
    }
    // ---- W staging geometry: thread t owns f = (t>>2) + 64p, k = (t&3)+4i.
    const int wF  = t >> 2;            // 0..63
    const int wK0 = t & 3;

    float acc[4][8];
    #pragma unroll
    for (int i = 0; i < 4; ++i)
        #pragma unroll
        for (int j = 0; j < 8; ++j) acc[i][j] = 0.0f;

    for (int ch = 0; ch < nch; ++ch) {
        const int c8 = c0 + ch * BC;
        __syncthreads();
        const float* xc = x + c8 * L_;
        #pragma unroll
        for (int i = 0; i < 9; ++i) {
            float v = 0.0f;
            if (poff[i] >= 0) v = xc[poff[i]];
            Pl[kP0 + 4 * i][mP] = v;
        }
        #pragma unroll
        for (int p = 0; p < 2; ++p) {
            const int f = wF + 64 * p;
            const float* wrow = Wg + (size_t)f * K_ + c8 * 9 + wK0;
            #pragma unroll
            for (int i = 0; i < 9; ++i) {
                Wl[wK0 + 4 * i][f] = wrow[4 * i];
            }
        }
        __syncthreads();
        #pragma unroll 6
        for (int k = 0; k < KC; ++k) {
            const float4 p  = *(const float4*)&Pl[k][tx * 4];
            const float4 wa = *(const float4*)&Wl[k][ty * 8];
            const float4 wb = *(const float4*)&Wl[k][ty * 8 + 4];
            const float pm[4] = {p.x, p.y, p.z, p.w};
            const float wn[8] = {wa.x, wa.y, wa.z, wa.w, wb.x, wb.y, wb.z, wb.w};
            #pragma unroll
            for (int i = 0; i < 4; ++i)
                #pragma unroll
                for (int j = 0; j < 8; ++j)
                    acc[i][j] += __builtin_fabsf(pm[i] - wn[j]);
        }
    }

    // store float4 across m: group [mb, mb+4) never straddles an image (4 | 784).
    const int mb = m0 + tx * 4;
    const int bI = mb / L_;
    const int lb = mb - bI * L_;
    float* slab = direct ? dst : dst + (size_t)blockIdx.z * SLAB;
    const float sgn = direct ? -1.0f : 1.0f;
    #pragma unroll
    for (int j = 0; j < 8; ++j) {
        const int f = ty * 8 + j;
        float4 v = make_float4(sgn * acc[0][j], sgn * acc[1][j],
                               sgn * acc[2][j], sgn * acc[3][j]);
        *(float4*)&slab[(size_t)(bI * F_ + f) * L_ + lb] = v;
    }
}

__global__ __launch_bounds__(256)
void adder2d_combine(const float* __restrict__ ws, float* __restrict__ out) {
    const int i = blockIdx.x * 256 + threadIdx.x;     // float4 index, SLAB/4 total
    const float4* a0 = (const float4*)ws;
    const float4* a1 = (const float4*)(ws + SLAB);
    const float4* a2 = (const float4*)(ws + 2 * (size_t)SLAB);
    const float4* a3 = (const float4*)(ws + 3 * (size_t)SLAB);
    float4 p0 = a0[i], p1 = a1[i], p2 = a2[i], p3 = a3[i];
    float4 r;
    r.x = -((p0.x + p1.x) + (p2.x + p3.x));
    r.y = -((p0.y + p1.y) + (p2.y + p3.y));
    r.z = -((p0.z + p1.z) + (p2.z + p3.z));
    r.w = -((p0.w + p1.w) + (p2.w + p3.w));
    ((float4*)out)[i] = r;
}

extern "C" void kernel_launch(void* const* d_in, const int* in_sizes, int n_in,
                              void* d_out, int out_size, void* d_ws, size_t ws_size,
                              hipStream_t stream) {
    const float* x = (const float*)d_in[0];   // [16,128,28,28]
    const float* W = (const float*)d_in[1];   // [128,128,3,3]
    float* out = (float*)d_out;               // [16,128,28,28]
    float* ws  = (float*)d_ws;

    const size_t needed = (size_t)SPLIT * SLAB * sizeof(float);  // ~25.7 MB
    if (ws_size >= needed) {
        dim3 grid(NMT, 1, SPLIT);             // (196, 1, 4) = 784 blocks
        adder2d_main<<<grid, 256, 0, stream>>>(x, W, ws, (C_ / BC) / SPLIT, 0);
        adder2d_combine<<<SLAB / 4 / 256, 256, 0, stream>>>(ws, out);
    } else {
        dim3 grid(NMT, 1, 1);                 // fallback: direct, no split
        adder2d_main<<<grid, 256, 0, stream>>>(x, W, out, C_ / BC, 1);
    }
}

// Round 3
// 204.926 us; speedup vs baseline: 2.2127x; 1.0465x over previous
//
#include <hip/hip_runtime.h>

// adder2d: out[b,f,l] = -sum_k |W[f,k] - P[b,k,l]|, P = 3x3/s1/p1 im2col of x.
// Round-2 geometry (TM=64, TF=128, BC=4, K-split x4 + combine) + software
// pipelining: prefetch chunk ch+1 global->regs during compute of chunk ch,
// raw s_barrier + manual lgkmcnt(0) instead of __syncthreads so prefetch
// loads stay in flight across the barrier (no vmcnt(0) drain).

#define B_   16
#define C_   128
#define HH   28
#define WW   28
#define F_   128
#define L_   (HH * WW)          // 784
#define K_   (C_ * 9)           // 1152
#define M_   (B_ * L_)          // 12544 = 196 * 64 exactly
#define BC   4                  // channels per LDS chunk
#define KC   (BC * 9)           // 36 k-steps per chunk
#define TM   64                 // m-tile
#define TF   128                // f-tile (all filters)
#define LDP  (TM + 4)           // 68 words
#define LDWR (TF + 4)           // 132 words
#define SPLIT 4                 // K-split factor
#define SLAB  (B_ * F_ * L_)    // 1,605,632 floats per partial slab
#define NMT  (M_ / TM)          // 196 m-tiles, exact

__global__ __launch_bounds__(256, 3)
void adder2d_main(const float* __restrict__ x, const float* __restrict__ Wg,
                  float* __restrict__ dst, int nch, int direct) {
    __shared__ __align__(16) float Pl[KC][LDP];    //  9,792 B
    __shared__ __align__(16) float Wl[KC][LDWR];   // 19,008 B

    const int t  = threadIdx.x;
    const int tx = t & 15;             // m-thread: 4 m each
    const int ty = t >> 4;             // f-thread: 8 f each
    const int m0 = blockIdx.x * TM;
    const int c0 = blockIdx.z * nch * BC;   // first channel of this split

    // ---- P staging geometry: thread t stages (k = (t>>6) + 4i, m = t&63), i<9.
    const int mP  = t & 63;
    const int kP0 = t >> 6;
    const int mG  = m0 + mP;
    int poff[9];
    {
        const int bI = mG / L_;
        const int lP = mG - bI * L_;
        const int ho = lP / WW, wo = lP - (lP / WW) * WW;
        const int bbase = bI * (C_ * L_);
        #pragma unroll
        for (int i = 0; i < 9; ++i) {
            const int kl = kP0 + 4 * i;
            const int cl = kl / 9, r = kl - cl * 9;
            const int kh = r / 3,  kw = r - (r / 3) * 3;
            const int y  = ho + kh - 1, xw = wo + kw - 1;
            const bool v = (y >= 0) && (y < HH) && (xw >= 0) && (xw < WW);
            poff[i] = v ? (bbase + cl * L_ + y * WW + xw) : -1;
        }
    }
    // ---- W staging geometry: thread t owns f = (t>>2) + 64p, k = (t&3)+4i.
    const int wF  = t >> 2;            // 0..63
    const int wK0 = t & 3;

    float acc[4][8];
    #pragma unroll
    for (int i = 0; i < 4; ++i)
        #pragma unroll
        for (int j = 0; j < 8; ++j) acc[i][j] = 0.0f;

    // ---- prologue: load chunk 0 into registers
    float pv[9], wvr[18];
    {
        const float* xc = x + c0 * L_;
        #pragma unroll
        for (int i = 0; i < 9; ++i)
            pv[i] = (poff[i] >= 0) ? xc[poff[i]] : 0.0f;
        #pragma unroll
        for (int p = 0; p < 2; ++p) {
            const float* wrow = Wg + (size_t)(wF + 64 * p) * K_ + c0 * 9 + wK0;
            #pragma unroll
            for (int i = 0; i < 9; ++i) wvr[p * 9 + i] = wrow[4 * i];
        }
    }

    for (int ch = 0; ch < nch; ++ch) {
        // ---- write staged regs -> LDS (vmcnt waits handled by compiler)
        #pragma unroll
        for (int i = 0; i < 9; ++i) Pl[kP0 + 4 * i][mP] = pv[i];
        #pragma unroll
        for (int p = 0; p < 2; ++p)
            #pragma unroll
            for (int i = 0; i < 9; ++i) Wl[wK0 + 4 * i][wF + 64 * p] = wvr[p * 9 + i];
        // ---- prefetch next chunk global->regs (in flight across the barrier)
        if (ch + 1 < nch) {
            const int c8 = c0 + (ch + 1) * BC;
            const float* xc = x + c8 * L_;
            #pragma unroll
            for (int i = 0; i < 9; ++i)
                pv[i] = (poff[i] >= 0) ? xc[poff[i]] : 0.0f;
            #pragma unroll
            for (int p = 0; p < 2; ++p) {
                const float* wrow = Wg + (size_t)(wF + 64 * p) * K_ + c8 * 9 + wK0;
                #pragma unroll
                for (int i = 0; i < 9; ++i) wvr[p * 9 + i] = wrow[4 * i];
            }
        }
        // ---- barrier WITHOUT vmcnt drain: only LDS writes must be done
        asm volatile("s_waitcnt lgkmcnt(0)" ::: "memory");
        __builtin_amdgcn_s_barrier();
        asm volatile("" ::: "memory");
        __builtin_amdgcn_sched_barrier(0);
        // ---- compute chunk
        #pragma unroll 9
        for (int k = 0; k < KC; ++k) {
            const float4 p  = *(const float4*)&Pl[k][tx * 4];
            const float4 wa = *(const float4*)&Wl[k][ty * 8];
            const float4 wb = *(const float4*)&Wl[k][ty * 8 + 4];
            const float pm[4] = {p.x, p.y, p.z, p.w};
            const float wn[8] = {wa.x, wa.y, wa.z, wa.w, wb.x, wb.y, wb.z, wb.w};
            #pragma unroll
            for (int i = 0; i < 4; ++i)
                #pragma unroll
                for (int j = 0; j < 8; ++j)
                    acc[i][j] += __builtin_fabsf(pm[i] - wn[j]);
        }
        // ---- all reads of this buffer done before next overwrite
        asm volatile("" ::: "memory");
        __builtin_amdgcn_sched_barrier(0);
        __builtin_amdgcn_s_barrier();
        asm volatile("" ::: "memory");
    }

    // store float4 across m: group [mb, mb+4) never straddles an image (4 | 784).
    const int mb = m0 + tx * 4;
    const int bI = mb / L_;
    const int lb = mb - bI * L_;
    float* slab = direct ? dst : dst + (size_t)blockIdx.z * SLAB;
    const float sgn = direct ? -1.0f : 1.0f;
    #pragma unroll
    for (int j = 0; j < 8; ++j) {
        const int f = ty * 8 + j;
        float4 v = make_float4(sgn * acc[0][j], sgn * acc[1][j],
                               sgn * acc[2][j], sgn * acc[3][j]);
        *(float4*)&slab[(size_t)(bI * F_ + f) * L_ + lb] = v;
    }
}

__global__ __launch_bounds__(256)
void adder2d_combine(const float* __restrict__ ws, float* __restrict__ out) {
    const int i = blockIdx.x * 256 + threadIdx.x;     // float4 index, SLAB/4 total
    const float4* a0 = (const float4*)ws;
    const float4* a1 = (const float4*)(ws + SLAB);
    const float4* a2 = (const float4*)(ws + 2 * (size_t)SLAB);
    const float4* a3 = (const float4*)(ws + 3 * (size_t)SLAB);
    float4 p0 = a0[i], p1 = a1[i], p2 = a2[i], p3 = a3[i];
    float4 r;
    r.x = -((p0.x + p1.x) + (p2.x + p3.x));
    r.y = -((p0.y + p1.y) + (p2.y + p3.y));
    r.z = -((p0.z + p1.z) + (p2.z + p3.z));
    r.w = -((p0.w + p1.w) + (p2.w + p3.w));
    ((float4*)out)[i] = r;
}

extern "C" void kernel_launch(void* const* d_in, const int* in_sizes, int n_in,
                              void* d_out, int out_size, void* d_ws, size_t ws_size,
                              hipStream_t stream) {
    const float* x = (const float*)d_in[0];   // [16,128,28,28]
    const float* W = (const float*)d_in[1];   // [128,128,3,3]
    float* out = (float*)d_out;               // [16,128,28,28]
    float* ws  = (float*)d_ws;

    const size_t needed = (size_t)SPLIT * SLAB * sizeof(float);  // ~25.7 MB
    if (ws_size >= needed) {
        dim3 grid(NMT, 1, SPLIT);             // (196, 1, 4) = 784 blocks
        adder2d_main<<<grid, 256, 0, stream>>>(x, W, ws, (C_ / BC) / SPLIT, 0);
        adder2d_combine<<<SLAB / 4 / 256, 256, 0, stream>>>(ws, out);
    } else {
        dim3 grid(NMT, 1, 1);                 // fallback: direct, no split
        adder2d_main<<<grid, 256, 0, stream>>>(x, W, out, C_ / BC, 1);
    }
}